// Round 1
// 2171.956 us; speedup vs baseline: 2.4398x; 2.4398x over previous
//
#include <hip/hip_runtime.h>
#include <math.h>

#define N   4096
#define NO  8192
#define TBL_ELEMS (128 * 128 * 32)   // g2 x r x k

#ifndef M_PI
#define M_PI 3.14159265358979323846
#endif

typedef __attribute__((ext_vector_type(8))) short short8;
typedef __attribute__((ext_vector_type(4))) float f32x4;

// ws layout (floats): [0..N) = wf interpolation weights, [N] = sign-sum S.
// At float offset 4352: table hi (ushort[TBL_ELEMS]), then table lo.
// Total workspace: 17408 B + 2*2*TBL_ELEMS B  ~= 2.02 MB.

__device__ __forceinline__ unsigned bf16h(float f) {
    unsigned u = __float_as_uint(f);
    return (u + 0x7FFFu + ((u >> 16) & 1u)) >> 16;   // RNE to bf16 bits
}

__global__ void init_weights_kernel(float* w) {
    int m = blockIdx.x * blockDim.x + threadIdx.x;
    if (m < N) {
        double ang = M_PI * (2.0 * (double)m + 1.0) / (2.0 * (double)N);
        double v = (cos(ang) / sin(ang)) / (double)N;
        w[m] = (m & 1) ? (float)(-v) : (float)v;
    }
    if (blockIdx.x == 0 && threadIdx.x == 0) w[N] = 0.0f;
}

// tbl[g][r][k] = wf[(r - k - 32*g) & (N-1)]  == W[t0+k][j0+r] for g=((t0-j0)/32)%128
__global__ void build_table_kernel(const float* __restrict__ wf,
                                   ushort* __restrict__ th, ushort* __restrict__ tl) {
    int idx = blockIdx.x * 256 + threadIdx.x;
    int k = idx & 31;
    int r = (idx >> 5) & 127;
    int g = idx >> 12;
    int m = (r - k - 32 * g) & (N - 1);
    float f = wf[m];
    unsigned h = bf16h(f);
    float hf = __uint_as_float(h << 16);
    unsigned l = bf16h(f - hf);
    th[idx] = (ushort)h;
    tl[idx] = (ushort)l;
}

__global__ void reduce_sign_kernel(const float* __restrict__ x, float* S) {
    const size_t NN = (size_t)N * N;
    float acc = 0.0f;
    for (size_t idx = (size_t)blockIdx.x * blockDim.x + threadIdx.x; idx < NN;
         idx += (size_t)gridDim.x * blockDim.x) {
        int st = (int)((idx >> 12) + (idx & (N - 1)));
        float v = x[idx];
        acc += (st & 1) ? -v : v;
    }
    #pragma unroll
    for (int off = 32; off > 0; off >>= 1) acc += __shfl_down(acc, off, 64);
    __shared__ float wsum[4];
    int lane = threadIdx.x & 63;
    int wv   = threadIdx.x >> 6;
    if (lane == 0) wsum[wv] = acc;
    __syncthreads();
    if (threadIdx.x == 0) atomicAdd(S, wsum[0] + wsum[1] + wsum[2] + wsum[3]);
}

__device__ __forceinline__ void split8(const float4& a0, const float4& a1,
                                       short8& hi, short8& lo) {
    float av[8] = {a0.x, a0.y, a0.z, a0.w, a1.x, a1.y, a1.z, a1.w};
    #pragma unroll
    for (int j = 0; j < 8; ++j) {
        unsigned h = bf16h(av[j]);
        float hf = __uint_as_float(h << 16);
        hi[j] = (short)h;
        lo[j] = (short)bf16h(av[j] - hf);
    }
}

// Horizontal pass: Z[s][j] = sum_t x[s][t] * w[(j-t) mod N]; writes even out rows.
__global__ __launch_bounds__(256) void hpass_mfma(const float* __restrict__ x,
                                                  const ushort* __restrict__ th,
                                                  const ushort* __restrict__ tl,
                                                  float* __restrict__ out) {
    const int j0 = blockIdx.x * 128;
    const int s0 = blockIdx.y * 128;
    const int tid = threadIdx.x;
    const int w   = tid >> 6;
    const int l   = tid & 63;
    const int lr  = l & 15;
    const int kb  = (l >> 4) * 8;
    const int wm  = (w >> 1) * 64;
    const int wn  = (w & 1) * 64;

    f32x4 acc[4][4];
    #pragma unroll
    for (int a = 0; a < 4; ++a)
        #pragma unroll
        for (int b = 0; b < 4; ++b)
            acc[a][b] = (f32x4){0.f, 0.f, 0.f, 0.f};

    for (int t0 = 0; t0 < N; t0 += 32) {
        const int g = ((t0 - j0) & (N - 1)) >> 5;
        short8 bh[4], bl[4];
        #pragma unroll
        for (int nf = 0; nf < 4; ++nf) {
            int r = wn + nf * 16 + lr;
            size_t flat = ((size_t)(g * 128 + r) << 5) + kb;
            bh[nf] = *reinterpret_cast<const short8*>(th + flat);
            bl[nf] = *reinterpret_cast<const short8*>(tl + flat);
        }
        #pragma unroll
        for (int mf = 0; mf < 4; ++mf) {
            const float* ap = x + (size_t)(s0 + wm + mf * 16 + lr) * N + (t0 + kb);
            float4 a0 = *reinterpret_cast<const float4*>(ap);
            float4 a1 = *reinterpret_cast<const float4*>(ap + 4);
            short8 ah, al;
            split8(a0, a1, ah, al);
            #pragma unroll
            for (int nf = 0; nf < 4; ++nf) {
                acc[mf][nf] = __builtin_amdgcn_mfma_f32_16x16x32_bf16(ah, bh[nf], acc[mf][nf], 0, 0, 0);
                acc[mf][nf] = __builtin_amdgcn_mfma_f32_16x16x32_bf16(ah, bl[nf], acc[mf][nf], 0, 0, 0);
                acc[mf][nf] = __builtin_amdgcn_mfma_f32_16x16x32_bf16(al, bh[nf], acc[mf][nf], 0, 0, 0);
            }
        }
    }

    const int crow = (l >> 4) * 4;
    #pragma unroll
    for (int mf = 0; mf < 4; ++mf) {
        #pragma unroll
        for (int i = 0; i < 4; ++i) {
            int s = s0 + wm + mf * 16 + crow + i;
            #pragma unroll
            for (int nf = 0; nf < 4; ++nf) {
                int j = j0 + wn + nf * 16 + lr;
                float xv = x[(size_t)s * N + j];
                float2 v2 = make_float2(xv, acc[mf][nf][i]);
                *reinterpret_cast<float2*>(out + (size_t)(2 * s) * NO + (size_t)(2 * j)) = v2;
            }
        }
    }
}

// Vertical pass: y[2i+1][b] = sum_s w[(i-s) mod N] * E[s][b]  - sign correction (odd b).
__global__ __launch_bounds__(256) void vpass_mfma(const ushort* __restrict__ th,
                                                  const ushort* __restrict__ tl,
                                                  const float* __restrict__ S,
                                                  float* out) {
    const int i0 = blockIdx.x * 128;   // i-tiles fastest: blocks sharing an E panel dispatch together
    const int b0 = blockIdx.y * 128;
    const int tid = threadIdx.x;
    const int w   = tid >> 6;
    const int l   = tid & 63;
    const int lr  = l & 15;
    const int kb  = (l >> 4) * 8;
    const int wm  = (w >> 1) * 64;
    const int wn  = (w & 1) * 64;

    f32x4 acc[4][4];
    #pragma unroll
    for (int a = 0; a < 4; ++a)
        #pragma unroll
        for (int b = 0; b < 4; ++b)
            acc[a][b] = (f32x4){0.f, 0.f, 0.f, 0.f};

    for (int s0 = 0; s0 < N; s0 += 32) {
        // B operand: E[s0+kb+j][colb], strided fp32 gather + in-reg split
        short8 bh[4], bl[4];
        #pragma unroll
        for (int nf = 0; nf < 4; ++nf) {
            int colb = b0 + wn + nf * 16 + lr;
            const float* ep = out + (size_t)(2 * (s0 + kb)) * NO + colb;
            float ev[8];
            #pragma unroll
            for (int j = 0; j < 8; ++j)
                ev[j] = ep[(size_t)(2 * j) * NO];
            #pragma unroll
            for (int j = 0; j < 8; ++j) {
                unsigned h = bf16h(ev[j]);
                float hf = __uint_as_float(h << 16);
                bh[nf][j] = (short)h;
                bl[nf][j] = (short)bf16h(ev[j] - hf);
            }
        }
        // A operand: circulant table, direct aligned fragment loads
        const int g = ((s0 - i0) & (N - 1)) >> 5;
        #pragma unroll
        for (int mf = 0; mf < 4; ++mf) {
            int r = wm + mf * 16 + lr;
            size_t flat = ((size_t)(g * 128 + r) << 5) + kb;
            short8 ah = *reinterpret_cast<const short8*>(th + flat);
            short8 al = *reinterpret_cast<const short8*>(tl + flat);
            #pragma unroll
            for (int nf = 0; nf < 4; ++nf) {
                acc[mf][nf] = __builtin_amdgcn_mfma_f32_16x16x32_bf16(ah, bh[nf], acc[mf][nf], 0, 0, 0);
                acc[mf][nf] = __builtin_amdgcn_mfma_f32_16x16x32_bf16(ah, bl[nf], acc[mf][nf], 0, 0, 0);
                acc[mf][nf] = __builtin_amdgcn_mfma_f32_16x16x32_bf16(al, bh[nf], acc[mf][nf], 0, 0, 0);
            }
        }
    }

    const float Sval = S[0] * (1.0f / ((float)N * (float)N));
    const int crow = (l >> 4) * 4;
    #pragma unroll
    for (int mf = 0; mf < 4; ++mf) {
        #pragma unroll
        for (int i = 0; i < 4; ++i) {
            int irow = i0 + wm + mf * 16 + crow + i;
            #pragma unroll
            for (int nf = 0; nf < 4; ++nf) {
                int b = b0 + wn + nf * 16 + lr;
                float v = acc[mf][nf][i];
                if (b & 1) {
                    int jdx = (b - 1) >> 1;
                    v -= (((irow + jdx) & 1) ? -Sval : Sval);
                }
                out[(size_t)(2 * irow + 1) * NO + (size_t)b] = v;
            }
        }
    }
}

extern "C" void kernel_launch(void* const* d_in, const int* in_sizes, int n_in,
                              void* d_out, int out_size, void* d_ws, size_t ws_size,
                              hipStream_t stream) {
    const float* x = (const float*)d_in[0];
    float* out = (float*)d_out;
    float* wf = (float*)d_ws;                      // N+1 floats
    ushort* th = (ushort*)(wf + 4352);             // TBL_ELEMS ushorts (1 MB)
    ushort* tl = th + TBL_ELEMS;                   // TBL_ELEMS ushorts (1 MB)

    init_weights_kernel<<<(N + 255) / 256, 256, 0, stream>>>(wf);
    build_table_kernel<<<TBL_ELEMS / 256, 256, 0, stream>>>(wf, th, tl);
    reduce_sign_kernel<<<1024, 256, 0, stream>>>(x, wf + N);

    dim3 hgrid(N / 128, N / 128);
    hpass_mfma<<<hgrid, 256, 0, stream>>>(x, th, tl, out);

    dim3 vgrid(N / 128, NO / 128);
    vpass_mfma<<<vgrid, 256, 0, stream>>>(th, tl, wf + N, out);
}